// Round 18
// baseline (1944.990 us; speedup 1.0000x reference)
//
#include <hip/hip_runtime.h>
#include <hip/hip_bf16.h>

#define B_   1024
#define S_   79
#define E_   512
#define H_   8
#define D_   64
#define LDX  (S_*E_)      // 40448
#define NROW 80896        // B_*S_

// d_out float layout (total 41,418,752 floats):
//   [0        : 12781568)  LG_BF16 : half-batch logits, 4096x6241 bf16
//   [13830144 : 14616576)  WSP     : wq/wk/wv bf16 hi/lo splits (ushorts)
//   [14616576 : 14649344)  BS_F32  : conv board-sum, 1024x32 fp32
//   [14649344 : 15452160)  SPP     : sproj bf16 hi/lo split (ushorts)
//   [15452160 : 15976448)  HSH     : hs bf16 hi, 8192x128 (ushorts)
//   [15976448 : 16500736)  HSL     : hs bf16 lo, 8192x128 (ushorts)
//   [20709376 : 41418752)  AO_BF16 : attn output, 80896x512 bf16 (top half)
// gemm_out overwrites everything with fp32 output via ascending ladder.
#define WSP_OFF 13830144u
#define BS_OFF  14616576u
#define SPP_OFF 14649344u
#define HSH_OFF 15452160u
#define HSL_OFF 15976448u
#define AO_OFF  20709376u

typedef __attribute__((ext_vector_type(8))) short short8v;   // 8 bf16
typedef __attribute__((ext_vector_type(4))) short short4v;
typedef __attribute__((ext_vector_type(4))) float f32x4;

__device__ __forceinline__ float silu_f(float s) {
    return s / (1.f + __expf(-s));
}

// RNE fp32 -> bf16 split: x ~= hi + lo (both bf16).
__device__ __forceinline__ void bsplit(float x, unsigned short& h,
                                       unsigned short& l) {
    unsigned u = __float_as_uint(x);
    unsigned hr = (u + 0x7fffu + ((u >> 16) & 1u)) >> 16;
    h = (unsigned short)hr;
    float r = x - __uint_as_float(hr << 16);
    unsigned u2 = __float_as_uint(r);
    l = (unsigned short)((u2 + 0x7fffu + ((u2 >> 16) & 1u)) >> 16);
}

// RNE fp32 -> bf16 (hi only)
__device__ __forceinline__ unsigned short brne(float x) {
    unsigned u = __float_as_uint(x);
    return (unsigned short)((u + 0x7fffu + ((u >> 16) & 1u)) >> 16);
}

// ---------------------------------------------------------------------------
// presplit_k: wq/wk/wv -> bf16 hi/lo in B-fragment layout (R8-validated).
// ---------------------------------------------------------------------------
__global__ __launch_bounds__(256) void presplit_k(
    const float* __restrict__ wq, const float* __restrict__ wk,
    const float* __restrict__ wv, unsigned short* __restrict__ wsp)
{
    const int idx = blockIdx.x * 256 + threadIdx.x;   // < 786432
    const int m = idx >> 18;
    const int r = idx & 262143;
    const int k = r >> 9, c = r & 511;
    const float* w = (m == 0) ? wq : (m == 1) ? wk : wv;
    unsigned short hh, ll;
    bsplit(w[(size_t)k * 512 + c], hh, ll);
    const size_t base = (size_t)m * 524288 + (size_t)(k >> 5) * 32768
                      + (size_t)c * 64 + (k & 31);
    wsp[base]      = hh;
    wsp[base + 32] = ll;
}

// ---------------------------------------------------------------------------
// presplit_sproj_k: sproj[128,6241] -> bf16 hi/lo in B-fragment layout.
// ---------------------------------------------------------------------------
__global__ __launch_bounds__(256) void presplit_sproj_k(
    const float* __restrict__ sproj, unsigned short* __restrict__ spp)
{
    const int idx = blockIdx.x * 256 + threadIdx.x;
    if (idx >= 128 * 6241) return;
    const int k = idx / 6241, c = idx - k * 6241;
    unsigned short hh, ll;
    bsplit(sproj[idx], hh, ll);
    const size_t base = ((size_t)(k >> 5) * 6272 + c) * 64 + (k & 31);
    spp[base]      = hh;
    spp[base + 32] = ll;
}

// ---------------------------------------------------------------------------
// conv01_k (R10-validated): conv0 + conv1 + mean, 31 KB LDS, 4 blocks/CU.
// ---------------------------------------------------------------------------
__global__ __launch_bounds__(256) void conv01_k(
    const float* __restrict__ xq,
    const float* __restrict__ c0w, const float* __restrict__ c0b,
    const float* __restrict__ c1w, const float* __restrict__ c1b,
    float* __restrict__ bsum)
{
    const int b = blockIdx.x, tid = threadIdx.x;
    __shared__ __attribute__((aligned(16))) float LB[6720];
    __shared__ __attribute__((aligned(16))) float h0[64][16];
    float (*xS)[33]      = (float (*)[33])LB;
    float (*wS)[32][16]  = (float (*)[32][16])(LB + 2112);
    float (*out2)[32]    = (float (*)[32])LB;
    float (*red)[32]     = (float (*)[32])(LB + 2048);

    const float* xb = xq + (size_t)b * LDX;
    const int px = tid >> 2, j = tid & 3;
    const int py = px >> 3, pxx = px & 7;

    float acc0[4];
#pragma unroll
    for (int i = 0; i < 4; ++i) acc0[i] = c0b[j * 4 + i];

    for (int kc = 0; kc < 512; kc += 32) {
        __syncthreads();
        for (int i = tid; i < 512; i += 256) {
            const int r = i >> 3, c4 = (i & 7) << 2;
            *(float4*)&xS[r][c4] =
                *(const float4*)&xb[(size_t)(1 + r) * 512 + kc + c4];
        }
        for (int i = tid; i < 1152; i += 256) {
            const int tap = i / 128, rem = i - tap * 128;
            const int c = rem >> 2, co4 = (rem & 3) << 2;
            *(float4*)&wS[tap][c][co4] =
                *(const float4*)&c0w[(size_t)(tap * 512 + kc + c) * 16 + co4];
        }
        __syncthreads();
        for (int ky = 0; ky < 3; ++ky) {
            const int yy = py + ky - 1;
            if (yy < 0 || yy > 7) continue;
            for (int kx = 0; kx < 3; ++kx) {
                const int xx2 = pxx + kx - 1;
                if (xx2 < 0 || xx2 > 7) continue;
                const float* xr = &xS[yy * 8 + xx2][0];
                const float* wr = &wS[ky * 3 + kx][0][j * 4];
#pragma unroll 8
                for (int c = 0; c < 32; ++c) {
                    const float xv = xr[c];
                    const float4 w4 = *(const float4*)&wr[c * 16];
                    acc0[0] = fmaf(xv, w4.x, acc0[0]);
                    acc0[1] = fmaf(xv, w4.y, acc0[1]);
                    acc0[2] = fmaf(xv, w4.z, acc0[2]);
                    acc0[3] = fmaf(xv, w4.w, acc0[3]);
                }
            }
        }
    }
#pragma unroll
    for (int i = 0; i < 4; ++i) h0[px][j * 4 + i] = fmaxf(acc0[i], 0.f);
    __syncthreads();

    {
        float acc[8];
#pragma unroll
        for (int i = 0; i < 8; ++i) acc[i] = c1b[j * 8 + i];
        for (int ky = 0; ky < 3; ++ky) {
            const int yy = py + ky - 1;
            if (yy < 0 || yy > 7) continue;
            for (int kx = 0; kx < 3; ++kx) {
                const int xx2 = pxx + kx - 1;
                if (xx2 < 0 || xx2 > 7) continue;
                const float* hr = &h0[yy * 8 + xx2][0];
                const float* wr = c1w + (size_t)(ky * 3 + kx) * 16 * 32 + j * 8;
#pragma unroll
                for (int c = 0; c < 16; ++c) {
                    const float hv = hr[c];
#pragma unroll
                    for (int i = 0; i < 8; ++i)
                        acc[i] = fmaf(hv, wr[c * 32 + i], acc[i]);
                }
            }
        }
#pragma unroll
        for (int i = 0; i < 8; ++i) out2[px][j * 8 + i] = fmaxf(acc[i], 0.f);
    }
    __syncthreads();

    {
        const int co = tid & 31, ch = tid >> 5;
        float s = 0.f;
#pragma unroll
        for (int p = ch * 8; p < ch * 8 + 8; ++p) s += out2[p][co];
        red[ch][co] = s;
    }
    __syncthreads();
    if (tid < 32) {
        float t = 0.f;
#pragma unroll
        for (int c2 = 0; c2 < 8; ++c2) t += red[c2][tid];
        bsum[(size_t)b * 32 + tid] = t * (1.f / 64.f);
    }
}

// ---------------------------------------------------------------------------
// smolgen_rest_k (R15-validated): special, g1 (ILP), g2, ps, hs -> bf16 hi/lo.
// ---------------------------------------------------------------------------
__global__ __launch_bounds__(256) void smolgen_rest_k(
    const float* __restrict__ xq,
    const float* __restrict__ sp_w, const float* __restrict__ sp_b,
    const float* __restrict__ g1w, const float* __restrict__ g1b,
    const float* __restrict__ g2w, const float* __restrict__ g2b,
    const float* __restrict__ sumw, const float* __restrict__ sumb,
    const float* __restrict__ headw, const float* __restrict__ headb,
    const float* __restrict__ bsum,
    unsigned short* __restrict__ hsH, unsigned short* __restrict__ hsL)
{
    const int b = blockIdx.x, tid = threadIdx.x;
    __shared__ float part[16][16];
    __shared__ float gpart[4][64];
    __shared__ float comb[80];
    __shared__ float psS[128];

    const float* xb = xq + (size_t)b * LDX;

    {
        const int o = tid & 15, p = tid >> 4;
        float s = 0.f;
        for (int c = p * 32; c < p * 32 + 32; ++c)
            s = fmaf(xb[c], sp_w[(size_t)c * 16 + o], s);
        part[p][o] = s;
    }
    {
        const int o = tid & 63, p = tid >> 6;
        const float* gx = xb + 65 * 512 + p * 1792;
        const float* gw = g1w + (size_t)(p * 1792) * 64 + o;
        float s0 = 0.f, s1 = 0.f, s2 = 0.f, s3 = 0.f;
        for (int gi = 0; gi < 1792; gi += 4) {
            s0 = fmaf(gx[gi + 0], gw[(size_t)(gi + 0) * 64], s0);
            s1 = fmaf(gx[gi + 1], gw[(size_t)(gi + 1) * 64], s1);
            s2 = fmaf(gx[gi + 2], gw[(size_t)(gi + 2) * 64], s2);
            s3 = fmaf(gx[gi + 3], gw[(size_t)(gi + 3) * 64], s3);
        }
        gpart[p][o] = (s0 + s1) + (s2 + s3);
    }
    __syncthreads();

    if (tid < 16) {
        float s = sp_b[tid];
#pragma unroll
        for (int p = 0; p < 16; ++p) s += part[p][tid];
        comb[tid] = fmaxf(s, 0.f);
    }
    if (tid >= 32 && tid < 64)
        comb[16 + (tid - 32)] = bsum[(size_t)b * 32 + (tid - 32)];
    if (tid < 64) {
        float s = g1b[tid];
#pragma unroll
        for (int p = 0; p < 4; ++p) s += gpart[p][tid];
        gpart[0][tid] = fmaxf(s, 0.f);
    }
    __syncthreads();

    if (tid >= 64 && tid < 96) {
        const int o = tid - 64;
        float s = g2b[o];
#pragma unroll
        for (int c = 0; c < 64; ++c)
            s = fmaf(gpart[0][c], g2w[c * 32 + o], s);
        comb[48 + o] = fmaxf(s, 0.f);
    }
    __syncthreads();

    if (tid < 128) {
        float s = sumb[tid];
#pragma unroll
        for (int c = 0; c < 80; ++c)
            s = fmaf(comb[c], sumw[(size_t)c * 128 + tid], s);
        psS[tid] = silu_f(s);
    }
    __syncthreads();

#pragma unroll
    for (int r = 0; r < 4; ++r) {
        const int o = tid + 256 * r;          // h*128 + i
        const int h = o >> 7, i = o & 127;
        float s = headb[o];
        const float* wr = headw + (size_t)h * 128 * 128 + i;
        float s0 = 0.f, s1 = 0.f, s2 = 0.f, s3 = 0.f;
#pragma unroll
        for (int c = 0; c < 128; c += 4) {
            s0 = fmaf(psS[c + 0], wr[(size_t)(c + 0) * 128], s0);
            s1 = fmaf(psS[c + 1], wr[(size_t)(c + 1) * 128], s1);
            s2 = fmaf(psS[c + 2], wr[(size_t)(c + 2) * 128], s2);
            s3 = fmaf(psS[c + 3], wr[(size_t)(c + 3) * 128], s3);
        }
        s += (s0 + s1) + (s2 + s3);
        unsigned short h_, l_;
        bsplit(silu_f(s), h_, l_);
        hsH[(size_t)b * 1024 + o] = h_;
        hsL[(size_t)b * 1024 + o] = l_;
    }
}

// ---------------------------------------------------------------------------
// lgemm_mfma_k (R15-validated): C = hs @ sproj via split-bf16 MFMA.
// ---------------------------------------------------------------------------
__global__ __launch_bounds__(256) void lgemm_mfma_k(
    const unsigned short* __restrict__ hsH,
    const unsigned short* __restrict__ hsL,
    const unsigned short* __restrict__ spp,
    __hip_bfloat16* __restrict__ C)
{
    const int tid = threadIdx.x;
    const int lane = tid & 63, w = tid >> 6;
    const int Lr = lane & 15, Lg = lane >> 4;
    const int row0 = blockIdx.y * 64;
    const int c0 = blockIdx.x * 64;
    const int cc = c0 + w * 16 + Lr;
    const int ccl = (cc < 6241) ? cc : 6240;

    f32x4 acc[4];
#pragma unroll
    for (int i = 0; i < 4; ++i) acc[i] = (f32x4){0.f, 0.f, 0.f, 0.f};

#pragma unroll
    for (int kc = 0; kc < 4; ++kc) {
        const size_t bOff = ((size_t)kc * 6272 + ccl) * 64 + Lg * 8;
        short8v bh = *(const short8v*)&spp[bOff];
        short8v bl = *(const short8v*)&spp[bOff + 32];
#pragma unroll
        for (int mt = 0; mt < 4; ++mt) {
            const size_t aOff = (size_t)(row0 + mt * 16 + Lr) * 128
                              + kc * 32 + Lg * 8;
            short8v ah = *(const short8v*)&hsH[aOff];
            short8v al = *(const short8v*)&hsL[aOff];
            acc[mt] = __builtin_amdgcn_mfma_f32_16x16x32_bf16(ah, bh, acc[mt], 0, 0, 0);
            acc[mt] = __builtin_amdgcn_mfma_f32_16x16x32_bf16(ah, bl, acc[mt], 0, 0, 0);
            acc[mt] = __builtin_amdgcn_mfma_f32_16x16x32_bf16(al, bh, acc[mt], 0, 0, 0);
        }
    }

    if (cc < 6241) {
#pragma unroll
        for (int mt = 0; mt < 4; ++mt) {
            const int rb = row0 + mt * 16 + Lg * 4;
#pragma unroll
            for (int r = 0; r < 4; ++r)
                C[(size_t)(rb + r) * 6241 + cc] = __float2bfloat16(acc[mt][r]);
        }
    }
}

// ---------------------------------------------------------------------------
// attn_half_k v10: v9 + (a) temporal+XCD swizzle: bl = (bid>>6)*8 + (bid&7),
// h = (bid>>3)&7 — same-batch blocks share bid%8 (XCD) AND sit within 64
// consecutive bids (co-resident -> x L2-hot); (b) double-buffered P1 staging
// (S0/S1) -> 1 barrier per chunk instead of 2.
// ---------------------------------------------------------------------------
#define STG_K 3200u    // k offset within a staging buffer (ushorts)

__global__ __launch_bounds__(512, 4) void attn_half_k(
    const float* __restrict__ xq, const float* __restrict__ xkv,
    const unsigned short* __restrict__ wsp,
    const __hip_bfloat16* __restrict__ lgB,
    __hip_bfloat16* __restrict__ outB, int b0)
{
    const int bid = blockIdx.x;
    const int bl = ((bid >> 6) << 3) + (bid & 7);   // batch
    const int h  = (bid >> 3) & 7;                  // head
    const int b = b0 + bl;
    const int tid = threadIdx.x;
    const int lane = tid & 63, w = tid >> 6;

    __shared__ __attribute__((aligned(16))) unsigned char Lds[72960];
    unsigned short* L16 = (unsigned short*)Lds;               // P1 staging
    unsigned short* QH  = (unsigned short*)(Lds);             // [80][72]
    unsigned short* QL  = (unsigned short*)(Lds + 11520);
    unsigned short* KH  = (unsigned short*)(Lds + 23040);
    unsigned short* KL  = (unsigned short*)(Lds + 34560);
    float*          scLg = (float*)(Lds + 46080);             // [80][84]
    unsigned short* PH  = (unsigned short*)(Lds);             // [80][104]
    unsigned short* PL  = (unsigned short*)(Lds + 16640);
    unsigned short* VBH = (unsigned short*)(Lds + 46080);     // [64][104]
    unsigned short* VBL = (unsigned short*)(Lds + 59392);

    const float* xqb = xq + (size_t)b * LDX;
    const float* xkb = xkv + (size_t)b * LDX;

    const int Lr = lane & 15, Lg = lane >> 4;
    const int ntw = w & 3;
    const int mtw = w >> 2;
    const int nTiles = (w < 4) ? 3 : 2;
    const int cB = ntw * 16 + Lr;
    const size_t wCol = (size_t)(h * 64 + cB) * 64 + Lg * 8;

    f32x4 accQ[3], accK[3], accV[3];
#pragma unroll
    for (int i = 0; i < 3; ++i) {
        accQ[i] = (f32x4){0.f, 0.f, 0.f, 0.f};
        accK[i] = (f32x4){0.f, 0.f, 0.f, 0.f};
        accV[i] = (f32x4){0.f, 0.f, 0.f, 0.f};
    }

    auto LD = [&](int ch, float4 (&xb)[3]) {
        const int k0 = ch * 32;
#pragma unroll
        for (int it = 0; it < 3; ++it) {
            const int i = tid + (it << 9);
            if (i < 1280) {
                const int s = (i >= 640);
                const int jj = i - s * 640;
                const int r = jj >> 3, k4 = (jj & 7) << 2;
                const float* src = s ? xkb : xqb;
                xb[it] = (r < 79)
                    ? *(const float4*)&src[(size_t)r * 512 + k0 + k4]
                    : (float4){0.f, 0.f, 0.f, 0.f};
            }
        }
    };
    auto STG = [&](float4 (&xb)[3], unsigned base) {
#pragma unroll
        for (int it = 0; it < 3; ++it) {
            const int i = tid + (it << 9);
            if (i < 1280) {
                const int s = (i >= 640);
                const int jj = i - s * 640;
                const int r = jj >> 3, k4 = (jj & 7) << 2;
                const unsigned off = base + (s ? STG_K : 0u) + r * 40 + k4;
                *(short4v*)&L16[off] = (short4v){
                    (short)brne(xb[it].x), (short)brne(xb[it].y),
                    (short)brne(xb[it].z), (short)brne(xb[it].w)};
            }
        }
    };
    auto MFMA_CHUNK = [&](int ch, unsigned base) {
        const size_t wOff = (size_t)ch * 32768 + wCol;
        short8v bhq = *(const short8v*)&wsp[wOff];
        short8v blq = *(const short8v*)&wsp[wOff + 32];
        short8v bhk = *(const short8v*)&wsp[524288 + wOff];
        short8v blk = *(const short8v*)&wsp[524288 + wOff + 32];
        short8v bhv = *(const short8v*)&wsp[1048576 + wOff];
#pragma unroll
        for (int i = 0; i < 3; ++i) {
            if (i < nTiles) {
                const int ar = (mtw + 2 * i) * 16 + Lr;
                short8v aq = *(const short8v*)&L16[base + ar * 40 + Lg * 8];
                accQ[i] = __builtin_amdgcn_mfma_f32_16x16x32_bf16(
                    aq, bhq, accQ[i], 0, 0, 0);
                accQ[i] = __builtin_amdgcn_mfma_f32_16x16x32_bf16(
                    aq, blq, accQ[i], 0, 0, 0);
                short8v ak = *(const short8v*)&L16[base + STG_K + ar * 40 + Lg * 8];
                accK[i] = __builtin_amdgcn_mfma_f32_16x16x32_bf16(
                    ak, bhk, accK[i], 0, 0, 0);
                accK[i] = __builtin_amdgcn_mfma_f32_16x16x32_bf16(
                    ak, blk, accK[i], 0, 0, 0);
                accV[i] = __builtin_amdgcn_mfma_f32_16x16x32_bf16(
                    ak, bhv, accV[i], 0, 0, 0);
            }
        }
    };

    // ---------------- phase 1: QKV (double-buffered staging) ----------------
    // S0 at ushort 0, S1 at ushort 6400; 1 barrier per chunk.
    float4 xbA[3], xbB[3];
    LD(0, xbA);
    STG(xbA, 0u);
    LD(1, xbB);
    __syncthreads();                       // S0 ready
    for (int ch = 0; ch < 16; ch += 2) {
        MFMA_CHUNK(ch, 0u);                // consume S0
        STG(xbB, 6400u);                   // fill S1 (prev S1 readers drained)
        if (ch + 2 < 16) LD(ch + 2, xbA);
        __syncthreads();                   // S1 ready
        MFMA_CHUNK(ch + 1, 6400u);         // consume S1
        if (ch + 2 < 16) {
            STG(xbA, 0u);                  // fill S0 (S0 readers drained:
            LD(ch + 3, xbB);               //  MFMA_CHUNK(ch,S0) precedes the
        }                                  //  barrier below in program order)
        __syncthreads();                   // S0 ready (or P1 done)
    }

    // epilogue: Q,K -> bf16 hi/lo (C layout: row = Lg*4+r, col = Lr)
#pragma unroll
    for (int i = 0; i < 3; ++i) {
        if (i < nTiles) {
            const int rb = (mtw + 2 * i) * 16 + Lg * 4;
            const int cc = ntw * 16 + Lr;
#pragma unroll
            for (int r = 0; r < 4; ++r) {
                const int row = rb + r;
                if (row < 79) {
                    unsigned short h_, l_;
                    bsplit(accQ[i][r], h_, l_);
                    QH[row * 72 + cc] = h_; QL[row * 72 + cc] = l_;
                    bsplit(accK[i][r], h_, l_);
                    KH[row * 72 + cc] = h_; KL[row * 72 + cc] = l_;
                }
            }
        }
    }
    __syncthreads();

    // ---------------- phase 2: scores via MFMA ----------------
    const __hip_bfloat16* lgp = lgB + (size_t)(bl * 8 + h) * 6241;
    for (int tt = w; tt < 25; tt += 8) {
        const int mt = tt / 5, nt = tt - mt * 5;
        const int aro = (mt * 16 + Lr) * 72;
        const int bro = (nt * 16 + Lr) * 72;
        f32x4 s = (f32x4){0.f, 0.f, 0.f, 0.f};
#pragma unroll
        for (int c = 0; c < 2; ++c) {
            const int ko = c * 32 + Lg * 8;
            short8v ah = *(const short8v*)&QH[aro + ko];
            short8v al = *(const short8v*)&QL[aro + ko];
            short8v bh2 = *(const short8v*)&KH[bro + ko];
            short8v bl2 = *(const short8v*)&KL[bro + ko];
            s = __builtin_amdgcn_mfma_f32_16x16x32_bf16(ah, bh2, s, 0, 0, 0);
            s = __builtin_amdgcn_mfma_f32_16x16x32_bf16(ah, bl2, s, 0, 0, 0);
            s = __builtin_amdgcn_mfma_f32_16x16x32_bf16(al, bh2, s, 0, 0, 0);
        }
        const int T = nt * 16 + Lr;
        const int t0 = mt * 16 + Lg * 4;
        if (T < 79) {
#pragma unroll
            for (int r = 0; r < 4; ++r) {
                const int t = t0 + r;
                if (t < 79)
                    scLg[t * 84 + T] = s[r] * 0.125f
                                     + __bfloat162float(lgp[t * 79 + T]);
            }
        }
    }
    __syncthreads();

    // ---------------- phase 3: softmax -> P bf16 hi/lo ----------------
    for (int t = w; t < 79; t += 8) {
        const float v1 = scLg[t * 84 + lane];
        const float v2 = (lane < 15) ? scLg[t * 84 + 64 + lane] : -3.0e38f;
        float m = fmaxf(v1, v2);
#pragma unroll
        for (int off = 32; off; off >>= 1)
            m = fmaxf(m, __shfl_xor(m, off));
        float e1 = __expf(v1 - m);
        float e2 = (lane < 15) ? __expf(v2 - m) : 0.f;
        float z = e1 + e2;
#pragma unroll
        for (int off = 32; off; off >>= 1)
            z += __shfl_xor(z, off);
        const float rz = 1.f / z;
        unsigned short h_, l_;
        bsplit(e1 * rz, h_, l_);
        PH[t * 104 + lane] = h_; PL[t * 104 + lane] = l_;
        if (lane < 15) {
            bsplit(e2 * rz, h_, l_);
            PH[t * 104 + 64 + lane] = h_; PL[t * 104 + 64 + lane] = l_;
        }
        if (lane >= 15 && lane < 40) {            // zero cols 79..103
            PH[t * 104 + 64 + lane] = 0; PL[t * 104 + 64 + lane] = 0;
        }
    }
    __syncthreads();   // scLg dead -> VB region usable

    // ---------------- phase 4a: V -> transposed bf16 hi/lo ----------------
#pragma unroll
    for (int i = 0; i < 3; ++i) {
        if (i < nTiles) {
            const int rb = (mtw + 2 * i) * 16 + Lg * 4;
            const int cc = ntw * 16 + Lr;
#pragma unroll
            for (int r = 0; r < 4; ++r) {
                const int row = rb + r;          // T index
                if (row < 79) {
                    unsigned short h_, l_;
                    bsplit(accV[i][r], h_, l_);
                    VBH[cc * 104 + row] = h_; VBL[cc * 104 + row] = l_;
                }
            }
        }
    }
    for (int i = tid; i < 64 * 17; i += 512) {    // zero cols 79..95
        const int d = i / 17, c = 79 + (i - d * 17);
        VBH[d * 104 + c] = 0; VBL[d * 104 + c] = 0;
    }
    __syncthreads();

    // ---------------- phase 4b: PV via MFMA -> AO ----------------
    for (int tt = w; tt < 20; tt += 8) {
        const int mt = tt >> 2, nt = tt & 3;
        const int aro = (mt * 16 + Lr) * 104;
        const int bro = (nt * 16 + Lr) * 104;
        f32x4 o = (f32x4){0.f, 0.f, 0.f, 0.f};
#pragma unroll
        for (int c = 0; c < 3; ++c) {
            const int To = c * 32 + Lg * 8;
            short8v pa = *(const short8v*)&PH[aro + To];
            short8v pb = *(const short8v*)&PL[aro + To];
            short8v vh = *(const short8v*)&VBH[bro + To];
            short8v vl = *(const short8v*)&VBL[bro + To];
            o = __builtin_amdgcn_mfma_f32_16x16x32_bf16(pa, vh, o, 0, 0, 0);
            o = __builtin_amdgcn_mfma_f32_16x16x32_bf16(pa, vl, o, 0, 0, 0);
            o = __builtin_amdgcn_mfma_f32_16x16x32_bf16(pb, vh, o, 0, 0, 0);
        }
        const int t0 = mt * 16 + Lg * 4;
        const int d = nt * 16 + Lr;
#pragma unroll
        for (int r = 0; r < 4; ++r) {
            const int t = t0 + r;
            if (t < 79)
                outB[((size_t)b * 79 + t) * 512 + h * 64 + d] =
                    __float2bfloat16(o[r]);
        }
    }
}

// ---------------------------------------------------------------------------
// gemm_out_mfma_k (R11-validated): C[r,:] = A_bf16[r,:] @ wo, rows [M0,M1).
// ---------------------------------------------------------------------------
__global__ __launch_bounds__(256) void gemm_out_mfma_k(
    const unsigned short* __restrict__ A, const float* __restrict__ wo,
    float* __restrict__ C, int M0, int M1, int nryP)
{
    __shared__ __attribute__((aligned(16))) unsigned short As[128 * 40];

    const int nry = (M1 - M0 + 127) >> 7;
    const int cx = blockIdx.x / nryP, ry = blockIdx.x % nryP;
    if (ry >= nry) return;

    const int tid = threadIdx.x;
    const int c0 = cx * 32;
    const int row0 = M0 + ry * 128;
    const int lane = tid & 63, w = tid >> 6;
    const int Lr = lane & 15, Lg = lane >> 4;
    const int nt = w >> 1, mg = w & 1;
    const int cB = nt * 16 + Lr;

    f32x4 acc[4];
#pragma unroll
    for (int i = 0; i < 4; ++i) acc[i] = (f32x4){0.f, 0.f, 0.f, 0.f};

    for (int ch = 0; ch < 16; ++ch) {
        const int k0 = ch * 32;
        const float* wop = wo + (size_t)(k0 + Lg * 8) * 512 + c0 + cB;
        unsigned short bhh[8], bll[8];
#pragma unroll
        for (int e = 0; e < 8; ++e)
            bsplit(wop[(size_t)e * 512], bhh[e], bll[e]);
        short8v bh = (short8v){(short)bhh[0], (short)bhh[1], (short)bhh[2],
                               (short)bhh[3], (short)bhh[4], (short)bhh[5],
                               (short)bhh[6], (short)bhh[7]};
        short8v bl = (short8v){(short)bll[0], (short)bll[1], (short)bll[2],
                               (short)bll[3], (short)bll[4], (short)bll[5],
                               (short)bll[6], (short)bll[7]};

        __syncthreads();
        for (int i = tid; i < 512; i += 256) {
            const int r = i >> 2, g = i & 3;
            int ar = row0 + r; if (ar > M1 - 1) ar = M1 - 1;
            *(short8v*)&As[r * 40 + g * 8] =
                *(const short8v*)&A[(size_t)ar * 512 + k0 + g * 8];
        }
        __syncthreads();
#pragma unroll
        for (int mt = 0; mt < 4; ++mt) {
            const int ar = mg * 64 + mt * 16 + Lr;
            short8v a = *(const short8v*)&As[ar * 40 + Lg * 8];
            acc[mt] = __builtin_amdgcn_mfma_f32_16x16x32_bf16(a, bh, acc[mt], 0, 0, 0);
            acc[mt] = __builtin_amdgcn_mfma_f32_16x16x32_bf16(a, bl, acc[mt], 0, 0, 0);
        }
    }

    // epilogue (all reads done)
#pragma unroll
    for (int mt = 0; mt < 4; ++mt) {
        const int rb = row0 + mg * 64 + mt * 16 + Lg * 4;
#pragma unroll
        for (int r = 0; r < 4; ++r) {
            const int row = rb + r;
            if (row < M1)
                C[(size_t)row * 512 + c0 + nt * 16 + Lr] = acc[mt][r];
        }
    }
}

// ---------------------------------------------------------------------------
extern "C" void kernel_launch(void* const* d_in, const int* in_sizes, int n_in,
                              void* d_out, int out_size, void* d_ws, size_t ws_size,
                              hipStream_t stream) {
    const float* xq    = (const float*)d_in[0];
    const float* xkv   = (const float*)d_in[1];
    const float* wq    = (const float*)d_in[2];
    const float* wk    = (const float*)d_in[3];
    const float* wv    = (const float*)d_in[4];
    const float* wo    = (const float*)d_in[5];
    const float* sp_w  = (const float*)d_in[6];
    const float* sp_b  = (const float*)d_in[7];
    const float* c0w   = (const float*)d_in[8];
    const float* c0b   = (const float*)d_in[9];
    const float* c1w   = (const float*)d_in[10];
    const float* c1b   = (const float*)d_in[11];
    const float* g1w   = (const float*)d_in[12];
    const float* g1b   = (const float*)d_in[13];
    const float* g2w   = (const float*)d_in[14];
    const float* g2b   = (const float*)d_in[15];
    const float* sumw  = (const float*)d_in[16];
    const float* sumb  = (const float*)d_in[17];
    const float* headw = (const float*)d_in[18];
    const float* headb = (const float*)d_in[19];
    const float* sproj = (const float*)d_in[20];
    float* out = (float*)d_out;

    // d_ws unusable in this harness (R1-R3 faulted on first touch; R4+ pass
    // with zero workspace). All intermediates live inside d_out.
    (void)d_ws; (void)ws_size; (void)in_sizes; (void)n_in; (void)out_size;

    __hip_bfloat16* lgB  = (__hip_bfloat16*)out;
    unsigned short* wsp  = (unsigned short*)(out + WSP_OFF);
    float* bsF           = out + BS_OFF;
    unsigned short* spp  = (unsigned short*)(out + SPP_OFF);
    unsigned short* hsH  = (unsigned short*)(out + HSH_OFF);
    unsigned short* hsL  = (unsigned short*)(out + HSL_OFF);
    __hip_bfloat16* outB = (__hip_bfloat16*)(out + AO_OFF);

    presplit_k<<<3072, 256, 0, stream>>>(wq, wk, wv, wsp);
    presplit_sproj_k<<<3121, 256, 0, stream>>>(sproj, spp);
    conv01_k<<<B_, 256, 0, stream>>>(xq, c0w, c0b, c1w, c1b, bsF);
    smolgen_rest_k<<<B_, 256, 0, stream>>>(xq, sp_w, sp_b, g1w, g1b,
                                           g2w, g2b, sumw, sumb,
                                           headw, headb, bsF, hsH, hsL);

    for (int half = 0; half < 2; ++half) {
        const unsigned short* hsHh = hsH + (size_t)half * 4096 * 128;
        const unsigned short* hsLh = hsL + (size_t)half * 4096 * 128;
        lgemm_mfma_k<<<dim3(98, 64), 256, 0, stream>>>(hsHh, hsLh, spp, lgB);
        attn_half_k<<<4096, 512, 0, stream>>>(xq, xkv, wsp, lgB, outB,
                                              half * 512);
    }

    // In-place output projection, ascending doubling ladder (R8+-validated).
    auto pass = [&](int lo, int hi) {
        const int nry = (hi - lo + 127) / 128;
        const int nryP = (nry + 7) & ~7;
        gemm_out_mfma_k<<<dim3(16 * nryP), 256, 0, stream>>>(
            (const unsigned short*)outB, wo, out, lo, hi, nryP);
    };
    pass(0, 40448);
    int lo = 40448;
    while (lo < NROW) {
        int hi = (NROW + lo) / 2;
        if (hi > 80768) hi = (lo < 80768) ? 80768 : NROW;
        pass(lo, hi);
        lo = hi;
    }
}

// Round 19
// 1848.758 us; speedup vs baseline: 1.0521x; 1.0521x over previous
//
#include <hip/hip_runtime.h>
#include <hip/hip_bf16.h>

#define B_   1024
#define S_   79
#define E_   512
#define H_   8
#define D_   64
#define LDX  (S_*E_)      // 40448
#define NROW 80896        // B_*S_

// d_out float layout (total 41,418,752 floats):
//   [0        : 12781568)  LG_BF16 : half-batch logits, 4096x6241 bf16
//   [13830144 : 14616576)  WSP     : wq/wk/wv bf16 hi/lo splits (ushorts)
//   [14616576 : 14649344)  BS_F32  : conv board-sum, 1024x32 fp32
//   [14649344 : 15452160)  SPP     : sproj bf16 hi/lo split (ushorts)
//   [15452160 : 15976448)  HSH     : hs bf16 hi, 8192x128 (ushorts)
//   [15976448 : 16500736)  HSL     : hs bf16 lo, 8192x128 (ushorts)
//   [20709376 : 41418752)  AO_BF16 : attn output, 80896x512 bf16 (top half)
// gemm_out overwrites everything with fp32 output via ascending ladder.
#define WSP_OFF 13830144u
#define BS_OFF  14616576u
#define SPP_OFF 14649344u
#define HSH_OFF 15452160u
#define HSL_OFF 15976448u
#define AO_OFF  20709376u

typedef __attribute__((ext_vector_type(8))) short short8v;   // 8 bf16
typedef __attribute__((ext_vector_type(4))) short short4v;
typedef __attribute__((ext_vector_type(4))) float f32x4;

__device__ __forceinline__ float silu_f(float s) {
    return s / (1.f + __expf(-s));
}

// RNE fp32 -> bf16 split: x ~= hi + lo (both bf16).
__device__ __forceinline__ void bsplit(float x, unsigned short& h,
                                       unsigned short& l) {
    unsigned u = __float_as_uint(x);
    unsigned hr = (u + 0x7fffu + ((u >> 16) & 1u)) >> 16;
    h = (unsigned short)hr;
    float r = x - __uint_as_float(hr << 16);
    unsigned u2 = __float_as_uint(r);
    l = (unsigned short)((u2 + 0x7fffu + ((u2 >> 16) & 1u)) >> 16);
}

// RNE fp32 -> bf16 (hi only)
__device__ __forceinline__ unsigned short brne(float x) {
    unsigned u = __float_as_uint(x);
    return (unsigned short)((u + 0x7fffu + ((u >> 16) & 1u)) >> 16);
}

// ---------------------------------------------------------------------------
// presplit_k: wq/wk/wv -> bf16 hi/lo in B-fragment layout (R8-validated).
// ---------------------------------------------------------------------------
__global__ __launch_bounds__(256) void presplit_k(
    const float* __restrict__ wq, const float* __restrict__ wk,
    const float* __restrict__ wv, unsigned short* __restrict__ wsp)
{
    const int idx = blockIdx.x * 256 + threadIdx.x;   // < 786432
    const int m = idx >> 18;
    const int r = idx & 262143;
    const int k = r >> 9, c = r & 511;
    const float* w = (m == 0) ? wq : (m == 1) ? wk : wv;
    unsigned short hh, ll;
    bsplit(w[(size_t)k * 512 + c], hh, ll);
    const size_t base = (size_t)m * 524288 + (size_t)(k >> 5) * 32768
                      + (size_t)c * 64 + (k & 31);
    wsp[base]      = hh;
    wsp[base + 32] = ll;
}

// ---------------------------------------------------------------------------
// presplit_sproj_k: sproj[128,6241] -> bf16 hi/lo in B-fragment layout.
// ---------------------------------------------------------------------------
__global__ __launch_bounds__(256) void presplit_sproj_k(
    const float* __restrict__ sproj, unsigned short* __restrict__ spp)
{
    const int idx = blockIdx.x * 256 + threadIdx.x;
    if (idx >= 128 * 6241) return;
    const int k = idx / 6241, c = idx - k * 6241;
    unsigned short hh, ll;
    bsplit(sproj[idx], hh, ll);
    const size_t base = ((size_t)(k >> 5) * 6272 + c) * 64 + (k & 31);
    spp[base]      = hh;
    spp[base + 32] = ll;
}

// ---------------------------------------------------------------------------
// conv01_k (R10-validated): conv0 + conv1 + mean, 31 KB LDS, 4 blocks/CU.
// ---------------------------------------------------------------------------
__global__ __launch_bounds__(256) void conv01_k(
    const float* __restrict__ xq,
    const float* __restrict__ c0w, const float* __restrict__ c0b,
    const float* __restrict__ c1w, const float* __restrict__ c1b,
    float* __restrict__ bsum)
{
    const int b = blockIdx.x, tid = threadIdx.x;
    __shared__ __attribute__((aligned(16))) float LB[6720];
    __shared__ __attribute__((aligned(16))) float h0[64][16];
    float (*xS)[33]      = (float (*)[33])LB;
    float (*wS)[32][16]  = (float (*)[32][16])(LB + 2112);
    float (*out2)[32]    = (float (*)[32])LB;
    float (*red)[32]     = (float (*)[32])(LB + 2048);

    const float* xb = xq + (size_t)b * LDX;
    const int px = tid >> 2, j = tid & 3;
    const int py = px >> 3, pxx = px & 7;

    float acc0[4];
#pragma unroll
    for (int i = 0; i < 4; ++i) acc0[i] = c0b[j * 4 + i];

    for (int kc = 0; kc < 512; kc += 32) {
        __syncthreads();
        for (int i = tid; i < 512; i += 256) {
            const int r = i >> 3, c4 = (i & 7) << 2;
            *(float4*)&xS[r][c4] =
                *(const float4*)&xb[(size_t)(1 + r) * 512 + kc + c4];
        }
        for (int i = tid; i < 1152; i += 256) {
            const int tap = i / 128, rem = i - tap * 128;
            const int c = rem >> 2, co4 = (rem & 3) << 2;
            *(float4*)&wS[tap][c][co4] =
                *(const float4*)&c0w[(size_t)(tap * 512 + kc + c) * 16 + co4];
        }
        __syncthreads();
        for (int ky = 0; ky < 3; ++ky) {
            const int yy = py + ky - 1;
            if (yy < 0 || yy > 7) continue;
            for (int kx = 0; kx < 3; ++kx) {
                const int xx2 = pxx + kx - 1;
                if (xx2 < 0 || xx2 > 7) continue;
                const float* xr = &xS[yy * 8 + xx2][0];
                const float* wr = &wS[ky * 3 + kx][0][j * 4];
#pragma unroll 8
                for (int c = 0; c < 32; ++c) {
                    const float xv = xr[c];
                    const float4 w4 = *(const float4*)&wr[c * 16];
                    acc0[0] = fmaf(xv, w4.x, acc0[0]);
                    acc0[1] = fmaf(xv, w4.y, acc0[1]);
                    acc0[2] = fmaf(xv, w4.z, acc0[2]);
                    acc0[3] = fmaf(xv, w4.w, acc0[3]);
                }
            }
        }
    }
#pragma unroll
    for (int i = 0; i < 4; ++i) h0[px][j * 4 + i] = fmaxf(acc0[i], 0.f);
    __syncthreads();

    {
        float acc[8];
#pragma unroll
        for (int i = 0; i < 8; ++i) acc[i] = c1b[j * 8 + i];
        for (int ky = 0; ky < 3; ++ky) {
            const int yy = py + ky - 1;
            if (yy < 0 || yy > 7) continue;
            for (int kx = 0; kx < 3; ++kx) {
                const int xx2 = pxx + kx - 1;
                if (xx2 < 0 || xx2 > 7) continue;
                const float* hr = &h0[yy * 8 + xx2][0];
                const float* wr = c1w + (size_t)(ky * 3 + kx) * 16 * 32 + j * 8;
#pragma unroll
                for (int c = 0; c < 16; ++c) {
                    const float hv = hr[c];
#pragma unroll
                    for (int i = 0; i < 8; ++i)
                        acc[i] = fmaf(hv, wr[c * 32 + i], acc[i]);
                }
            }
        }
#pragma unroll
        for (int i = 0; i < 8; ++i) out2[px][j * 8 + i] = fmaxf(acc[i], 0.f);
    }
    __syncthreads();

    {
        const int co = tid & 31, ch = tid >> 5;
        float s = 0.f;
#pragma unroll
        for (int p = ch * 8; p < ch * 8 + 8; ++p) s += out2[p][co];
        red[ch][co] = s;
    }
    __syncthreads();
    if (tid < 32) {
        float t = 0.f;
#pragma unroll
        for (int c2 = 0; c2 < 8; ++c2) t += red[c2][tid];
        bsum[(size_t)b * 32 + tid] = t * (1.f / 64.f);
    }
}

// ---------------------------------------------------------------------------
// smolgen_rest_k (R15-validated): special, g1 (ILP), g2, ps, hs -> bf16 hi/lo.
// ---------------------------------------------------------------------------
__global__ __launch_bounds__(256) void smolgen_rest_k(
    const float* __restrict__ xq,
    const float* __restrict__ sp_w, const float* __restrict__ sp_b,
    const float* __restrict__ g1w, const float* __restrict__ g1b,
    const float* __restrict__ g2w, const float* __restrict__ g2b,
    const float* __restrict__ sumw, const float* __restrict__ sumb,
    const float* __restrict__ headw, const float* __restrict__ headb,
    const float* __restrict__ bsum,
    unsigned short* __restrict__ hsH, unsigned short* __restrict__ hsL)
{
    const int b = blockIdx.x, tid = threadIdx.x;
    __shared__ float part[16][16];
    __shared__ float gpart[4][64];
    __shared__ float comb[80];
    __shared__ float psS[128];

    const float* xb = xq + (size_t)b * LDX;

    {
        const int o = tid & 15, p = tid >> 4;
        float s = 0.f;
        for (int c = p * 32; c < p * 32 + 32; ++c)
            s = fmaf(xb[c], sp_w[(size_t)c * 16 + o], s);
        part[p][o] = s;
    }
    {
        const int o = tid & 63, p = tid >> 6;
        const float* gx = xb + 65 * 512 + p * 1792;
        const float* gw = g1w + (size_t)(p * 1792) * 64 + o;
        float s0 = 0.f, s1 = 0.f, s2 = 0.f, s3 = 0.f;
        for (int gi = 0; gi < 1792; gi += 4) {
            s0 = fmaf(gx[gi + 0], gw[(size_t)(gi + 0) * 64], s0);
            s1 = fmaf(gx[gi + 1], gw[(size_t)(gi + 1) * 64], s1);
            s2 = fmaf(gx[gi + 2], gw[(size_t)(gi + 2) * 64], s2);
            s3 = fmaf(gx[gi + 3], gw[(size_t)(gi + 3) * 64], s3);
        }
        gpart[p][o] = (s0 + s1) + (s2 + s3);
    }
    __syncthreads();

    if (tid < 16) {
        float s = sp_b[tid];
#pragma unroll
        for (int p = 0; p < 16; ++p) s += part[p][tid];
        comb[tid] = fmaxf(s, 0.f);
    }
    if (tid >= 32 && tid < 64)
        comb[16 + (tid - 32)] = bsum[(size_t)b * 32 + (tid - 32)];
    if (tid < 64) {
        float s = g1b[tid];
#pragma unroll
        for (int p = 0; p < 4; ++p) s += gpart[p][tid];
        gpart[0][tid] = fmaxf(s, 0.f);
    }
    __syncthreads();

    if (tid >= 64 && tid < 96) {
        const int o = tid - 64;
        float s = g2b[o];
#pragma unroll
        for (int c = 0; c < 64; ++c)
            s = fmaf(gpart[0][c], g2w[c * 32 + o], s);
        comb[48 + o] = fmaxf(s, 0.f);
    }
    __syncthreads();

    if (tid < 128) {
        float s = sumb[tid];
#pragma unroll
        for (int c = 0; c < 80; ++c)
            s = fmaf(comb[c], sumw[(size_t)c * 128 + tid], s);
        psS[tid] = silu_f(s);
    }
    __syncthreads();

#pragma unroll
    for (int r = 0; r < 4; ++r) {
        const int o = tid + 256 * r;          // h*128 + i
        const int h = o >> 7, i = o & 127;
        float s = headb[o];
        const float* wr = headw + (size_t)h * 128 * 128 + i;
        float s0 = 0.f, s1 = 0.f, s2 = 0.f, s3 = 0.f;
#pragma unroll
        for (int c = 0; c < 128; c += 4) {
            s0 = fmaf(psS[c + 0], wr[(size_t)(c + 0) * 128], s0);
            s1 = fmaf(psS[c + 1], wr[(size_t)(c + 1) * 128], s1);
            s2 = fmaf(psS[c + 2], wr[(size_t)(c + 2) * 128], s2);
            s3 = fmaf(psS[c + 3], wr[(size_t)(c + 3) * 128], s3);
        }
        s += (s0 + s1) + (s2 + s3);
        unsigned short h_, l_;
        bsplit(silu_f(s), h_, l_);
        hsH[(size_t)b * 1024 + o] = h_;
        hsL[(size_t)b * 1024 + o] = l_;
    }
}

// ---------------------------------------------------------------------------
// lgemm_mfma_k (R15-validated): C = hs @ sproj via split-bf16 MFMA.
// ---------------------------------------------------------------------------
__global__ __launch_bounds__(256) void lgemm_mfma_k(
    const unsigned short* __restrict__ hsH,
    const unsigned short* __restrict__ hsL,
    const unsigned short* __restrict__ spp,
    __hip_bfloat16* __restrict__ C)
{
    const int tid = threadIdx.x;
    const int lane = tid & 63, w = tid >> 6;
    const int Lr = lane & 15, Lg = lane >> 4;
    const int row0 = blockIdx.y * 64;
    const int c0 = blockIdx.x * 64;
    const int cc = c0 + w * 16 + Lr;
    const int ccl = (cc < 6241) ? cc : 6240;

    f32x4 acc[4];
#pragma unroll
    for (int i = 0; i < 4; ++i) acc[i] = (f32x4){0.f, 0.f, 0.f, 0.f};

#pragma unroll
    for (int kc = 0; kc < 4; ++kc) {
        const size_t bOff = ((size_t)kc * 6272 + ccl) * 64 + Lg * 8;
        short8v bh = *(const short8v*)&spp[bOff];
        short8v bl = *(const short8v*)&spp[bOff + 32];
#pragma unroll
        for (int mt = 0; mt < 4; ++mt) {
            const size_t aOff = (size_t)(row0 + mt * 16 + Lr) * 128
                              + kc * 32 + Lg * 8;
            short8v ah = *(const short8v*)&hsH[aOff];
            short8v al = *(const short8v*)&hsL[aOff];
            acc[mt] = __builtin_amdgcn_mfma_f32_16x16x32_bf16(ah, bh, acc[mt], 0, 0, 0);
            acc[mt] = __builtin_amdgcn_mfma_f32_16x16x32_bf16(ah, bl, acc[mt], 0, 0, 0);
            acc[mt] = __builtin_amdgcn_mfma_f32_16x16x32_bf16(al, bh, acc[mt], 0, 0, 0);
        }
    }

    if (cc < 6241) {
#pragma unroll
        for (int mt = 0; mt < 4; ++mt) {
            const int rb = row0 + mt * 16 + Lg * 4;
#pragma unroll
            for (int r = 0; r < 4; ++r)
                C[(size_t)(rb + r) * 6241 + cc] = __float2bfloat16(acc[mt][r]);
        }
    }
}

// ---------------------------------------------------------------------------
// attn_half_k v11: R16's v9 pipelined schedule (validated 455 us) + R18's
// temporal+XCD swizzle decode only (FETCH 694->204 MB, traffic-proven).
// A/B isolation: if this is >480 us, the swizzle itself is the cost.
// ---------------------------------------------------------------------------
#define XHq 0u
#define XHk 3200u

__global__ __launch_bounds__(512, 4) void attn_half_k(
    const float* __restrict__ xq, const float* __restrict__ xkv,
    const unsigned short* __restrict__ wsp,
    const __hip_bfloat16* __restrict__ lgB,
    __hip_bfloat16* __restrict__ outB, int b0)
{
    const int bid = blockIdx.x;
    const int bl = ((bid >> 6) << 3) + (bid & 7);   // batch (temporal+XCD)
    const int h  = (bid >> 3) & 7;                  // head
    const int b = b0 + bl;
    const int tid = threadIdx.x;
    const int lane = tid & 63, w = tid >> 6;

    __shared__ __attribute__((aligned(16))) unsigned char Lds[72960];
    unsigned short* L16 = (unsigned short*)Lds;               // P1 staging
    unsigned short* QH  = (unsigned short*)(Lds);             // [80][72]
    unsigned short* QL  = (unsigned short*)(Lds + 11520);
    unsigned short* KH  = (unsigned short*)(Lds + 23040);
    unsigned short* KL  = (unsigned short*)(Lds + 34560);
    float*          scLg = (float*)(Lds + 46080);             // [80][84]
    unsigned short* PH  = (unsigned short*)(Lds);             // [80][104]
    unsigned short* PL  = (unsigned short*)(Lds + 16640);
    unsigned short* VBH = (unsigned short*)(Lds + 46080);     // [64][104]
    unsigned short* VBL = (unsigned short*)(Lds + 59392);

    const float* xqb = xq + (size_t)b * LDX;
    const float* xkb = xkv + (size_t)b * LDX;

    const int Lr = lane & 15, Lg = lane >> 4;
    const int ntw = w & 3;
    const int mtw = w >> 2;
    const int nTiles = (w < 4) ? 3 : 2;
    const int cB = ntw * 16 + Lr;
    const size_t wCol = (size_t)(h * 64 + cB) * 64 + Lg * 8;

    f32x4 accQ[3], accK[3], accV[3];
#pragma unroll
    for (int i = 0; i < 3; ++i) {
        accQ[i] = (f32x4){0.f, 0.f, 0.f, 0.f};
        accK[i] = (f32x4){0.f, 0.f, 0.f, 0.f};
        accV[i] = (f32x4){0.f, 0.f, 0.f, 0.f};
    }

    auto LD = [&](int ch, float4 (&xb)[3]) {
        const int k0 = ch * 32;
#pragma unroll
        for (int it = 0; it < 3; ++it) {
            const int i = tid + (it << 9);
            if (i < 1280) {
                const int s = (i >= 640);
                const int jj = i - s * 640;
                const int r = jj >> 3, k4 = (jj & 7) << 2;
                const float* src = s ? xkb : xqb;
                xb[it] = (r < 79)
                    ? *(const float4*)&src[(size_t)r * 512 + k0 + k4]
                    : (float4){0.f, 0.f, 0.f, 0.f};
            }
        }
    };
    auto STG = [&](float4 (&xb)[3]) {
#pragma unroll
        for (int it = 0; it < 3; ++it) {
            const int i = tid + (it << 9);
            if (i < 1280) {
                const int s = (i >= 640);
                const int jj = i - s * 640;
                const int r = jj >> 3, k4 = (jj & 7) << 2;
                const unsigned bh_ = s ? XHk : XHq;
                *(short4v*)&L16[bh_ + r * 40 + k4] = (short4v){
                    (short)brne(xb[it].x), (short)brne(xb[it].y),
                    (short)brne(xb[it].z), (short)brne(xb[it].w)};
            }
        }
    };
    auto DO_CHUNK = [&](float4 (&xb)[3], int ch) {
        const size_t wOff = (size_t)ch * 32768 + wCol;
        short8v bhq = *(const short8v*)&wsp[wOff];
        short8v blq = *(const short8v*)&wsp[wOff + 32];
        short8v bhk = *(const short8v*)&wsp[524288 + wOff];
        short8v blk = *(const short8v*)&wsp[524288 + wOff + 32];
        short8v bhv = *(const short8v*)&wsp[1048576 + wOff];
        __syncthreads();     // prev MFMA done reading staging
        STG(xb);
        __syncthreads();
#pragma unroll
        for (int i = 0; i < 3; ++i) {
            if (i < nTiles) {
                const int ar = (mtw + 2 * i) * 16 + Lr;
                short8v aq = *(const short8v*)&L16[XHq + ar * 40 + Lg * 8];
                accQ[i] = __builtin_amdgcn_mfma_f32_16x16x32_bf16(
                    aq, bhq, accQ[i], 0, 0, 0);
                accQ[i] = __builtin_amdgcn_mfma_f32_16x16x32_bf16(
                    aq, blq, accQ[i], 0, 0, 0);
                short8v ak = *(const short8v*)&L16[XHk + ar * 40 + Lg * 8];
                accK[i] = __builtin_amdgcn_mfma_f32_16x16x32_bf16(
                    ak, bhk, accK[i], 0, 0, 0);
                accK[i] = __builtin_amdgcn_mfma_f32_16x16x32_bf16(
                    ak, blk, accK[i], 0, 0, 0);
                accV[i] = __builtin_amdgcn_mfma_f32_16x16x32_bf16(
                    ak, bhv, accV[i], 0, 0, 0);
            }
        }
    };

    // ---------------- phase 1: QKV (pipelined, v9 schedule) ----------------
    float4 xbufA[3], xbufB[3];
    LD(0, xbufA);
    for (int ch = 0; ch < 16; ch += 2) {
        LD(ch + 1, xbufB);
        DO_CHUNK(xbufA, ch);
        if (ch + 2 < 16) LD(ch + 2, xbufA);
        DO_CHUNK(xbufB, ch + 1);
    }
    __syncthreads();   // staging dead

    // epilogue: Q,K -> bf16 hi/lo (C layout: row = Lg*4+r, col = Lr)
#pragma unroll
    for (int i = 0; i < 3; ++i) {
        if (i < nTiles) {
            const int rb = (mtw + 2 * i) * 16 + Lg * 4;
            const int cc = ntw * 16 + Lr;
#pragma unroll
            for (int r = 0; r < 4; ++r) {
                const int row = rb + r;
                if (row < 79) {
                    unsigned short h_, l_;
                    bsplit(accQ[i][r], h_, l_);
                    QH[row * 72 + cc] = h_; QL[row * 72 + cc] = l_;
                    bsplit(accK[i][r], h_, l_);
                    KH[row * 72 + cc] = h_; KL[row * 72 + cc] = l_;
                }
            }
        }
    }
    __syncthreads();

    // ---------------- phase 2: scores via MFMA ----------------
    const __hip_bfloat16* lgp = lgB + (size_t)(bl * 8 + h) * 6241;
    for (int tt = w; tt < 25; tt += 8) {
        const int mt = tt / 5, nt = tt - mt * 5;
        const int aro = (mt * 16 + Lr) * 72;
        const int bro = (nt * 16 + Lr) * 72;
        f32x4 s = (f32x4){0.f, 0.f, 0.f, 0.f};
#pragma unroll
        for (int c = 0; c < 2; ++c) {
            const int ko = c * 32 + Lg * 8;
            short8v ah = *(const short8v*)&QH[aro + ko];
            short8v al = *(const short8v*)&QL[aro + ko];
            short8v bh2 = *(const short8v*)&KH[bro + ko];
            short8v bl2 = *(const short8v*)&KL[bro + ko];
            s = __builtin_amdgcn_mfma_f32_16x16x32_bf16(ah, bh2, s, 0, 0, 0);
            s = __builtin_amdgcn_mfma_f32_16x16x32_bf16(ah, bl2, s, 0, 0, 0);
            s = __builtin_amdgcn_mfma_f32_16x16x32_bf16(al, bh2, s, 0, 0, 0);
        }
        const int T = nt * 16 + Lr;
        const int t0 = mt * 16 + Lg * 4;
        if (T < 79) {
#pragma unroll
            for (int r = 0; r < 4; ++r) {
                const int t = t0 + r;
                if (t < 79)
                    scLg[t * 84 + T] = s[r] * 0.125f
                                     + __bfloat162float(lgp[t * 79 + T]);
            }
        }
    }
    __syncthreads();

    // ---------------- phase 3: softmax -> P bf16 hi/lo ----------------
    for (int t = w; t < 79; t += 8) {
        const float v1 = scLg[t * 84 + lane];
        const float v2 = (lane < 15) ? scLg[t * 84 + 64 + lane] : -3.0e38f;
        float m = fmaxf(v1, v2);
#pragma unroll
        for (int off = 32; off; off >>= 1)
            m = fmaxf(m, __shfl_xor(m, off));
        float e1 = __expf(v1 - m);
        float e2 = (lane < 15) ? __expf(v2 - m) : 0.f;
        float z = e1 + e2;
#pragma unroll
        for (int off = 32; off; off >>= 1)
            z += __shfl_xor(z, off);
        const float rz = 1.f / z;
        unsigned short h_, l_;
        bsplit(e1 * rz, h_, l_);
        PH[t * 104 + lane] = h_; PL[t * 104 + lane] = l_;
        if (lane < 15) {
            bsplit(e2 * rz, h_, l_);
            PH[t * 104 + 64 + lane] = h_; PL[t * 104 + 64 + lane] = l_;
        }
        if (lane >= 15 && lane < 40) {            // zero cols 79..103
            PH[t * 104 + 64 + lane] = 0; PL[t * 104 + 64 + lane] = 0;
        }
    }
    __syncthreads();   // scLg dead -> VB region usable

    // ---------------- phase 4a: V -> transposed bf16 hi/lo ----------------
#pragma unroll
    for (int i = 0; i < 3; ++i) {
        if (i < nTiles) {
            const int rb = (mtw + 2 * i) * 16 + Lg * 4;
            const int cc = ntw * 16 + Lr;
#pragma unroll
            for (int r = 0; r < 4; ++r) {
                const int row = rb + r;          // T index
                if (row < 79) {
                    unsigned short h_, l_;
                    bsplit(accV[i][r], h_, l_);
                    VBH[cc * 104 + row] = h_; VBL[cc * 104 + row] = l_;
                }
            }
        }
    }
    for (int i = tid; i < 64 * 17; i += 512) {    // zero cols 79..95
        const int d = i / 17, c = 79 + (i - d * 17);
        VBH[d * 104 + c] = 0; VBL[d * 104 + c] = 0;
    }
    __syncthreads();

    // ---------------- phase 4b: PV via MFMA -> AO ----------------
    for (int tt = w; tt < 20; tt += 8) {
        const int mt = tt >> 2, nt = tt & 3;
        const int aro = (mt * 16 + Lr) * 104;
        const int bro = (nt * 16 + Lr) * 104;
        f32x4 o = (f32x4){0.f, 0.f, 0.f, 0.f};
#pragma unroll
        for (int c = 0; c < 3; ++c) {
            const int To = c * 32 + Lg * 8;
            short8v pa = *(const short8v*)&PH[aro + To];
            short8v pb = *(const short8v*)&PL[aro + To];
            short8v vh = *(const short8v*)&VBH[bro + To];
            short8v vl = *(const short8v*)&VBL[bro + To];
            o = __builtin_amdgcn_mfma_f32_16x16x32_bf16(pa, vh, o, 0, 0, 0);
            o = __builtin_amdgcn_mfma_f32_16x16x32_bf16(pa, vl, o, 0, 0, 0);
            o = __builtin_amdgcn_mfma_f32_16x16x32_bf16(pb, vh, o, 0, 0, 0);
        }
        const int t0 = mt * 16 + Lg * 4;
        const int d = nt * 16 + Lr;
#pragma unroll
        for (int r = 0; r < 4; ++r) {
            const int t = t0 + r;
            if (t < 79)
                outB[((size_t)b * 79 + t) * 512 + h * 64 + d] =
                    __float2bfloat16(o[r]);
        }
    }
}

// ---------------------------------------------------------------------------
// gemm_out_mfma_k (R11-validated): C[r,:] = A_bf16[r,:] @ wo, rows [M0,M1).
// ---------------------------------------------------------------------------
__global__ __launch_bounds__(256) void gemm_out_mfma_k(
    const unsigned short* __restrict__ A, const float* __restrict__ wo,
    float* __restrict__ C, int M0, int M1, int nryP)
{
    __shared__ __attribute__((aligned(16))) unsigned short As[128 * 40];

    const int nry = (M1 - M0 + 127) >> 7;
    const int cx = blockIdx.x / nryP, ry = blockIdx.x % nryP;
    if (ry >= nry) return;

    const int tid = threadIdx.x;
    const int c0 = cx * 32;
    const int row0 = M0 + ry * 128;
    const int lane = tid & 63, w = tid >> 6;
    const int Lr = lane & 15, Lg = lane >> 4;
    const int nt = w >> 1, mg = w & 1;
    const int cB = nt * 16 + Lr;

    f32x4 acc[4];
#pragma unroll
    for (int i = 0; i < 4; ++i) acc[i] = (f32x4){0.f, 0.f, 0.f, 0.f};

    for (int ch = 0; ch < 16; ++ch) {
        const int k0 = ch * 32;
        const float* wop = wo + (size_t)(k0 + Lg * 8) * 512 + c0 + cB;
        unsigned short bhh[8], bll[8];
#pragma unroll
        for (int e = 0; e < 8; ++e)
            bsplit(wop[(size_t)e * 512], bhh[e], bll[e]);
        short8v bh = (short8v){(short)bhh[0], (short)bhh[1], (short)bhh[2],
                               (short)bhh[3], (short)bhh[4], (short)bhh[5],
                               (short)bhh[6], (short)bhh[7]};
        short8v bl = (short8v){(short)bll[0], (short)bll[1], (short)bll[2],
                               (short)bll[3], (short)bll[4], (short)bll[5],
                               (short)bll[6], (short)bll[7]};

        __syncthreads();
        for (int i = tid; i < 512; i += 256) {
            const int r = i >> 2, g = i & 3;
            int ar = row0 + r; if (ar > M1 - 1) ar = M1 - 1;
            *(short8v*)&As[r * 40 + g * 8] =
                *(const short8v*)&A[(size_t)ar * 512 + k0 + g * 8];
        }
        __syncthreads();
#pragma unroll
        for (int mt = 0; mt < 4; ++mt) {
            const int ar = mg * 64 + mt * 16 + Lr;
            short8v a = *(const short8v*)&As[ar * 40 + Lg * 8];
            acc[mt] = __builtin_amdgcn_mfma_f32_16x16x32_bf16(a, bh, acc[mt], 0, 0, 0);
            acc[mt] = __builtin_amdgcn_mfma_f32_16x16x32_bf16(a, bl, acc[mt], 0, 0, 0);
        }
    }

    // epilogue (all reads done)
#pragma unroll
    for (int mt = 0; mt < 4; ++mt) {
        const int rb = row0 + mg * 64 + mt * 16 + Lg * 4;
#pragma unroll
        for (int r = 0; r < 4; ++r) {
            const int row = rb + r;
            if (row < M1)
                C[(size_t)row * 512 + c0 + nt * 16 + Lr] = acc[mt][r];
        }
    }
}

// ---------------------------------------------------------------------------
extern "C" void kernel_launch(void* const* d_in, const int* in_sizes, int n_in,
                              void* d_out, int out_size, void* d_ws, size_t ws_size,
                              hipStream_t stream) {
    const float* xq    = (const float*)d_in[0];
    const float* xkv   = (const float*)d_in[1];
    const float* wq    = (const float*)d_in[2];
    const float* wk    = (const float*)d_in[3];
    const float* wv    = (const float*)d_in[4];
    const float* wo    = (const float*)d_in[5];
    const float* sp_w  = (const float*)d_in[6];
    const float* sp_b  = (const float*)d_in[7];
    const float* c0w   = (const float*)d_in[8];
    const float* c0b   = (const float*)d_in[9];
    const float* c1w   = (const float*)d_in[10];
    const float* c1b   = (const float*)d_in[11];
    const float* g1w   = (const float*)d_in[12];
    const float* g1b   = (const float*)d_in[13];
    const float* g2w   = (const float*)d_in[14];
    const float* g2b   = (const float*)d_in[15];
    const float* sumw  = (const float*)d_in[16];
    const float* sumb  = (const float*)d_in[17];
    const float* headw = (const float*)d_in[18];
    const float* headb = (const float*)d_in[19];
    const float* sproj = (const float*)d_in[20];
    float* out = (float*)d_out;

    // d_ws unusable in this harness (R1-R3 faulted on first touch; R4+ pass
    // with zero workspace). All intermediates live inside d_out.
    (void)d_ws; (void)ws_size; (void)in_sizes; (void)n_in; (void)out_size;

    __hip_bfloat16* lgB  = (__hip_bfloat16*)out;
    unsigned short* wsp  = (unsigned short*)(out + WSP_OFF);
    float* bsF           = out + BS_OFF;
    unsigned short* spp  = (unsigned short*)(out + SPP_OFF);
    unsigned short* hsH  = (unsigned short*)(out + HSH_OFF);
    unsigned short* hsL  = (unsigned short*)(out + HSL_OFF);
    __hip_bfloat16* outB = (__hip_bfloat16*)(out + AO_OFF);

    presplit_k<<<3072, 256, 0, stream>>>(wq, wk, wv, wsp);
    presplit_sproj_k<<<3121, 256, 0, stream>>>(sproj, spp);
    conv01_k<<<B_, 256, 0, stream>>>(xq, c0w, c0b, c1w, c1b, bsF);
    smolgen_rest_k<<<B_, 256, 0, stream>>>(xq, sp_w, sp_b, g1w, g1b,
                                           g2w, g2b, sumw, sumb,
                                           headw, headb, bsF, hsH, hsL);

    for (int half = 0; half < 2; ++half) {
        const unsigned short* hsHh = hsH + (size_t)half * 4096 * 128;
        const unsigned short* hsLh = hsL + (size_t)half * 4096 * 128;
        lgemm_mfma_k<<<dim3(98, 64), 256, 0, stream>>>(hsHh, hsLh, spp, lgB);
        attn_half_k<<<4096, 512, 0, stream>>>(xq, xkv, wsp, lgB, outB,
                                              half * 512);
    }

    // In-place output projection, ascending doubling ladder (R8+-validated).
    auto pass = [&](int lo, int hi) {
        const int nry = (hi - lo + 127) / 128;
        const int nryP = (nry + 7) & ~7;
        gemm_out_mfma_k<<<dim3(16 * nryP), 256, 0, stream>>>(
            (const unsigned short*)outB, wo, out, lo, hi, nryP);
    };
    pass(0, 40448);
    int lo = 40448;
    while (lo < NROW) {
        int hi = (NROW + lo) / 2;
        if (hi > 80768) hi = (lo < 80768) ? 80768 : NROW;
        pass(lo, hi);
        lo = hi;
    }
}